// Round 4
// baseline (255.805 us; speedup 1.0000x reference)
//
#include <hip/hip_runtime.h>
#include <hip/hip_bf16.h>

// Problem constants (MoEAggregator_455266533835)
#define B_SZ 2
#define S_SZ 2048
#define D_SZ 4096
#define N_ADP 8

// native clang vector type — required by __builtin_nontemporal_load/store
typedef float f4_t __attribute__((ext_vector_type(4)));

// ---------------------------------------------------------------------------
// Kernel 1: gate logits. One block per (batch, adapter): g[b,n] =
// dot(x[b,S-1,:], gate_W[n,:]). 16 blocks x 256 threads, float4-vectorized.
// Writes raw logits (no bias) to ws[b*8+n]; every byte written each call.
// ---------------------------------------------------------------------------
__global__ void moe_gate_dot(const f4_t* __restrict__ x4,
                             const f4_t* __restrict__ gateW4,
                             float* __restrict__ g_out) {
    const int n = blockIdx.x;
    const int b = blockIdx.y;
    const f4_t* xrow = x4 + ((size_t)b * S_SZ + (S_SZ - 1)) * (D_SZ / 4);
    const f4_t* wrow = gateW4 + (size_t)n * (D_SZ / 4);

    float s = 0.f;
#pragma unroll
    for (int i = 0; i < D_SZ / 4 / 256; ++i) {  // 4 iterations
        const int d4 = i * 256 + threadIdx.x;
        const f4_t xv = xrow[d4];
        const f4_t wv = wrow[d4];
        s += xv.x * wv.x + xv.y * wv.y + xv.z * wv.z + xv.w * wv.w;
    }

    // wave reduce
#pragma unroll
    for (int off = 32; off > 0; off >>= 1)
        s += __shfl_down(s, off, 64);

    __shared__ float red[4];
    const int wave = threadIdx.x >> 6;
    const int lane = threadIdx.x & 63;
    if (lane == 0) red[wave] = s;
    __syncthreads();
    if (threadIdx.x == 0)
        g_out[b * N_ADP + n] = red[0] + red[1] + red[2] + red[3];
}

// ---------------------------------------------------------------------------
// Kernel 2: per-thread redundant top-k from the 16 logits (L2-hit, ~free),
// then stream: out[b,s,d] = base + sum_n w[n]*lora[...,n].
// Nontemporal loads/stores: zero-reuse streams, don't thrash L2/L3.
// ---------------------------------------------------------------------------
__global__ __launch_bounds__(256, 4) void moe_aggregate(
        const f4_t* __restrict__ base4,
        const f4_t* __restrict__ lora4,
        const float* __restrict__ g_ws,
        const float* __restrict__ gate_b,
        const int* __restrict__ top_k_p,
        f4_t* __restrict__ out4) {
    const int b = blockIdx.y;

    // top-k selection (redundant per thread; values wave-uniform)
    float g[N_ADP];
#pragma unroll
    for (int n = 0; n < N_ADP; ++n) g[n] = g_ws[b * N_ADP + n] + gate_b[n];

    float w[N_ADP];
#pragma unroll
    for (int n = 0; n < N_ADP; ++n) w[n] = 0.f;
    {
        const int k = *top_k_p;
        for (int t = 0; t < k && t < N_ADP; ++t) {
            int best = -1;
            float bv = 0.f;
#pragma unroll
            for (int n = 0; n < N_ADP; ++n) {
                if (w[n] == 0.f && (best < 0 || g[n] > bv)) {
                    bv = g[n];
                    best = n;
                }
            }
            w[best] = 1.f;
        }
    }
    const float w0 = w[0], w1 = w[1], w2 = w[2], w3 = w[3];
    const float w4 = w[4], w5 = w[5], w6 = w[6], w7 = w[7];

    const size_t outq_batch = (size_t)S_SZ * D_SZ / 4;  // 2M output quads
    const size_t obase_off = (size_t)b * outq_batch;
    const int nq = (int)outq_batch;

    const int stride = gridDim.x * blockDim.x;
    for (int q = blockIdx.x * blockDim.x + threadIdx.x; q < nq; q += stride) {
        const size_t o = obase_off + (size_t)q;
        const f4_t bv = __builtin_nontemporal_load(base4 + o);
        const f4_t* lp = lora4 + o * N_ADP;  // 8 quads per output quad

        f4_t l[8];
#pragma unroll
        for (int j = 0; j < 8; ++j)
            l[j] = __builtin_nontemporal_load(lp + j);

        f4_t ov;
        ov.x = bv.x + w0 * l[0].x + w1 * l[0].y + w2 * l[0].z + w3 * l[0].w
                    + w4 * l[1].x + w5 * l[1].y + w6 * l[1].z + w7 * l[1].w;
        ov.y = bv.y + w0 * l[2].x + w1 * l[2].y + w2 * l[2].z + w3 * l[2].w
                    + w4 * l[3].x + w5 * l[3].y + w6 * l[3].z + w7 * l[3].w;
        ov.z = bv.z + w0 * l[4].x + w1 * l[4].y + w2 * l[4].z + w3 * l[4].w
                    + w4 * l[5].x + w5 * l[5].y + w6 * l[5].z + w7 * l[5].w;
        ov.w = bv.w + w0 * l[6].x + w1 * l[6].y + w2 * l[6].z + w3 * l[6].w
                    + w4 * l[7].x + w5 * l[7].y + w6 * l[7].z + w7 * l[7].w;
        __builtin_nontemporal_store(ov, out4 + o);
    }
}

extern "C" void kernel_launch(void* const* d_in, const int* in_sizes, int n_in,
                              void* d_out, int out_size, void* d_ws, size_t ws_size,
                              hipStream_t stream) {
    const float* x        = (const float*)d_in[0];
    const float* base_res = (const float*)d_in[1];
    const float* lora     = (const float*)d_in[2];
    const float* gate_W   = (const float*)d_in[3];
    const float* gate_b   = (const float*)d_in[4];
    const int*   top_k    = (const int*)d_in[5];
    float* out  = (float*)d_out;
    float* g_ws = (float*)d_ws;  // B*N raw gate logits, fully rewritten per call

    moe_gate_dot<<<dim3(N_ADP, B_SZ), dim3(256), 0, stream>>>(
        (const f4_t*)x, (const f4_t*)gate_W, g_ws);

    moe_aggregate<<<dim3(1024, B_SZ), dim3(256), 0, stream>>>(
        (const f4_t*)base_res, (const f4_t*)lora, g_ws, gate_b, top_k,
        (f4_t*)out);
}

// Round 5
// 139.705 us; speedup vs baseline: 1.8310x; 1.8310x over previous
//
#include <hip/hip_runtime.h>
#include <hip/hip_bf16.h>

// Problem constants (MoEAggregator_455266533835)
#define B_SZ 2
#define S_SZ 2048
#define D_SZ 4096
#define N_ADP 8

// ---------------------------------------------------------------------------
// Kernel 1: gate logits. One block per (batch, adapter): g[b,n] =
// dot(x[b,S-1,:], gate_W[n,:]). 16 blocks x 256 threads, float4-vectorized.
// Writes raw logits (no bias) to ws[b*8+n]; every byte rewritten each call.
// ---------------------------------------------------------------------------
__global__ void moe_gate_dot(const float4* __restrict__ x4,
                             const float4* __restrict__ gateW4,
                             float* __restrict__ g_out) {
    const int n = blockIdx.x;
    const int b = blockIdx.y;
    const float4* xrow = x4 + ((size_t)b * S_SZ + (S_SZ - 1)) * (D_SZ / 4);
    const float4* wrow = gateW4 + (size_t)n * (D_SZ / 4);

    float s = 0.f;
#pragma unroll
    for (int i = 0; i < D_SZ / 4 / 256; ++i) {  // 4 iterations
        const int d4 = i * 256 + threadIdx.x;
        const float4 xv = xrow[d4];
        const float4 wv = wrow[d4];
        s += xv.x * wv.x + xv.y * wv.y + xv.z * wv.z + xv.w * wv.w;
    }

    // wave reduce (wave = 64)
#pragma unroll
    for (int off = 32; off > 0; off >>= 1)
        s += __shfl_down(s, off, 64);

    __shared__ float red[4];
    const int wave = threadIdx.x >> 6;
    const int lane = threadIdx.x & 63;
    if (lane == 0) red[wave] = s;
    __syncthreads();
    if (threadIdx.x == 0)
        g_out[b * N_ADP + n] = red[0] + red[1] + red[2] + red[3];
}

// ---------------------------------------------------------------------------
// Kernel 2: per-thread redundant top-k from the 16 logits (L2-hit, ~free),
// then stream: out[b,s,d] = base + sum_n w[n]*lora[...,n].
// Plain cached loads (nt hurt: 8 same-line loads per lane stop collapsing).
// ---------------------------------------------------------------------------
__global__ void moe_aggregate(
        const float4* __restrict__ base4,
        const float4* __restrict__ lora4,
        const float* __restrict__ g_ws,
        const float* __restrict__ gate_b,
        const int* __restrict__ top_k_p,
        float4* __restrict__ out4) {
    const int b = blockIdx.y;

    // top-k selection (redundant per thread; values wave-uniform)
    float g[N_ADP];
#pragma unroll
    for (int n = 0; n < N_ADP; ++n) g[n] = g_ws[b * N_ADP + n] + gate_b[n];

    float w[N_ADP];
#pragma unroll
    for (int n = 0; n < N_ADP; ++n) w[n] = 0.f;
    {
        const int k = *top_k_p;
        for (int t = 0; t < k && t < N_ADP; ++t) {
            int best = -1;
            float bv = 0.f;
#pragma unroll
            for (int n = 0; n < N_ADP; ++n) {
                if (w[n] == 0.f && (best < 0 || g[n] > bv)) {
                    bv = g[n];
                    best = n;
                }
            }
            w[best] = 1.f;
        }
    }
    const float w0 = w[0], w1 = w[1], w2 = w[2], w3 = w[3];
    const float w4 = w[4], w5 = w[5], w6 = w[6], w7 = w[7];

    const size_t outq_batch = (size_t)S_SZ * D_SZ / 4;  // 2M output quads
    const size_t obase_off = (size_t)b * outq_batch;
    const int nq = (int)outq_batch;

    const int stride = gridDim.x * blockDim.x;
    for (int q = blockIdx.x * blockDim.x + threadIdx.x; q < nq; q += stride) {
        const size_t o = obase_off + (size_t)q;
        const float4 bv = base4[o];
        const float4* lp = lora4 + o * N_ADP;  // 8 quads per output quad

        float4 l[8];
#pragma unroll
        for (int j = 0; j < 8; ++j) l[j] = lp[j];

        float4 ov;
        ov.x = bv.x + w0 * l[0].x + w1 * l[0].y + w2 * l[0].z + w3 * l[0].w
                    + w4 * l[1].x + w5 * l[1].y + w6 * l[1].z + w7 * l[1].w;
        ov.y = bv.y + w0 * l[2].x + w1 * l[2].y + w2 * l[2].z + w3 * l[2].w
                    + w4 * l[3].x + w5 * l[3].y + w6 * l[3].z + w7 * l[3].w;
        ov.z = bv.z + w0 * l[4].x + w1 * l[4].y + w2 * l[4].z + w3 * l[4].w
                    + w4 * l[5].x + w5 * l[5].y + w6 * l[5].z + w7 * l[5].w;
        ov.w = bv.w + w0 * l[6].x + w1 * l[6].y + w2 * l[6].z + w3 * l[6].w
                    + w4 * l[7].x + w5 * l[7].y + w6 * l[7].z + w7 * l[7].w;
        out4[o] = ov;
    }
}

extern "C" void kernel_launch(void* const* d_in, const int* in_sizes, int n_in,
                              void* d_out, int out_size, void* d_ws, size_t ws_size,
                              hipStream_t stream) {
    const float* x        = (const float*)d_in[0];
    const float* base_res = (const float*)d_in[1];
    const float* lora     = (const float*)d_in[2];
    const float* gate_W   = (const float*)d_in[3];
    const float* gate_b   = (const float*)d_in[4];
    const int*   top_k    = (const int*)d_in[5];
    float* out  = (float*)d_out;
    float* g_ws = (float*)d_ws;  // B*N raw gate logits, fully rewritten per call

    moe_gate_dot<<<dim3(N_ADP, B_SZ), dim3(256), 0, stream>>>(
        (const float4*)x, (const float4*)gate_W, g_ws);

    moe_aggregate<<<dim3(2048, B_SZ), dim3(256), 0, stream>>>(
        (const float4*)base_res, (const float4*)lora, g_ws, gate_b, top_k,
        (float4*)out);
}

// Round 6
// 137.658 us; speedup vs baseline: 1.8583x; 1.0149x over previous
//
#include <hip/hip_runtime.h>
#include <hip/hip_bf16.h>

// Problem constants (MoEAggregator_455266533835)
#define B_SZ 2
#define S_SZ 2048
#define D_SZ 4096
#define N_ADP 8

// ---------------------------------------------------------------------------
// Kernel 1: gate logits. One block per (batch, adapter): g[b,n] =
// dot(x[b,S-1,:], gate_W[n,:]). 16 blocks x 256 threads, float4-vectorized.
// Writes raw logits (no bias) to ws[b*8+n]; every byte rewritten each call.
// ---------------------------------------------------------------------------
__global__ void moe_gate_dot(const float4* __restrict__ x4,
                             const float4* __restrict__ gateW4,
                             float* __restrict__ g_out) {
    const int n = blockIdx.x;
    const int b = blockIdx.y;
    const float4* xrow = x4 + ((size_t)b * S_SZ + (S_SZ - 1)) * (D_SZ / 4);
    const float4* wrow = gateW4 + (size_t)n * (D_SZ / 4);

    float s = 0.f;
#pragma unroll
    for (int i = 0; i < D_SZ / 4 / 256; ++i) {  // 4 iterations
        const int d4 = i * 256 + threadIdx.x;
        const float4 xv = xrow[d4];
        const float4 wv = wrow[d4];
        s += xv.x * wv.x + xv.y * wv.y + xv.z * wv.z + xv.w * wv.w;
    }

    // wave reduce (wave = 64)
#pragma unroll
    for (int off = 32; off > 0; off >>= 1)
        s += __shfl_down(s, off, 64);

    __shared__ float red[4];
    const int wave = threadIdx.x >> 6;
    const int lane = threadIdx.x & 63;
    if (lane == 0) red[wave] = s;
    __syncthreads();
    if (threadIdx.x == 0)
        g_out[b * N_ADP + n] = red[0] + red[1] + red[2] + red[3];
}

// ---------------------------------------------------------------------------
// Kernel 2: per-thread redundant top-k (L2-hit, ~free), then stream.
// 2 output quads per thread per iteration: 256B contiguous lora + 32B base
// reads, 32B store. 18 loads in flight per thread-iteration (vs 9 before);
// 16KB contiguous lora per wave-iteration (vs 8KB).
// ---------------------------------------------------------------------------
__global__ void moe_aggregate(
        const float4* __restrict__ base4,
        const float4* __restrict__ lora4,
        const float* __restrict__ g_ws,
        const float* __restrict__ gate_b,
        const int* __restrict__ top_k_p,
        float4* __restrict__ out4) {
    const int b = blockIdx.y;

    // top-k selection (redundant per thread; values wave-uniform)
    float g[N_ADP];
#pragma unroll
    for (int n = 0; n < N_ADP; ++n) g[n] = g_ws[b * N_ADP + n] + gate_b[n];

    float w[N_ADP];
#pragma unroll
    for (int n = 0; n < N_ADP; ++n) w[n] = 0.f;
    {
        const int k = *top_k_p;
        for (int t = 0; t < k && t < N_ADP; ++t) {
            int best = -1;
            float bv = 0.f;
#pragma unroll
            for (int n = 0; n < N_ADP; ++n) {
                if (w[n] == 0.f && (best < 0 || g[n] > bv)) {
                    bv = g[n];
                    best = n;
                }
            }
            w[best] = 1.f;
        }
    }
    const float w0 = w[0], w1 = w[1], w2 = w[2], w3 = w[3];
    const float w4 = w[4], w5 = w[5], w6 = w[6], w7 = w[7];

    const size_t outq_batch = (size_t)S_SZ * D_SZ / 4;  // 2M output quads
    const size_t obase_off = (size_t)b * outq_batch;
    const int npairs = (int)(outq_batch / 2);  // 1M pairs per batch

    const int stride = gridDim.x * blockDim.x;  // 524288
    for (int p = blockIdx.x * blockDim.x + threadIdx.x; p < npairs; p += stride) {
        const size_t o = obase_off + (size_t)p * 2;
        const float4 bv0 = base4[o];
        const float4 bv1 = base4[o + 1];
        const float4* lp = lora4 + o * N_ADP;  // 16 quads (256B) contiguous

        float4 l[16];
#pragma unroll
        for (int j = 0; j < 16; ++j) l[j] = lp[j];

        float4 ov0, ov1;
        ov0.x = bv0.x + w0 * l[0].x + w1 * l[0].y + w2 * l[0].z + w3 * l[0].w
                      + w4 * l[1].x + w5 * l[1].y + w6 * l[1].z + w7 * l[1].w;
        ov0.y = bv0.y + w0 * l[2].x + w1 * l[2].y + w2 * l[2].z + w3 * l[2].w
                      + w4 * l[3].x + w5 * l[3].y + w6 * l[3].z + w7 * l[3].w;
        ov0.z = bv0.z + w0 * l[4].x + w1 * l[4].y + w2 * l[4].z + w3 * l[4].w
                      + w4 * l[5].x + w5 * l[5].y + w6 * l[5].z + w7 * l[5].w;
        ov0.w = bv0.w + w0 * l[6].x + w1 * l[6].y + w2 * l[6].z + w3 * l[6].w
                      + w4 * l[7].x + w5 * l[7].y + w6 * l[7].z + w7 * l[7].w;
        ov1.x = bv1.x + w0 * l[8].x + w1 * l[8].y + w2 * l[8].z + w3 * l[8].w
                      + w4 * l[9].x + w5 * l[9].y + w6 * l[9].z + w7 * l[9].w;
        ov1.y = bv1.y + w0 * l[10].x + w1 * l[10].y + w2 * l[10].z + w3 * l[10].w
                      + w4 * l[11].x + w5 * l[11].y + w6 * l[11].z + w7 * l[11].w;
        ov1.z = bv1.z + w0 * l[12].x + w1 * l[12].y + w2 * l[12].z + w3 * l[12].w
                      + w4 * l[13].x + w5 * l[13].y + w6 * l[13].z + w7 * l[13].w;
        ov1.w = bv1.w + w0 * l[14].x + w1 * l[14].y + w2 * l[14].z + w3 * l[14].w
                      + w4 * l[15].x + w5 * l[15].y + w6 * l[15].z + w7 * l[15].w;
        out4[o] = ov0;
        out4[o + 1] = ov1;
    }
}

extern "C" void kernel_launch(void* const* d_in, const int* in_sizes, int n_in,
                              void* d_out, int out_size, void* d_ws, size_t ws_size,
                              hipStream_t stream) {
    const float* x        = (const float*)d_in[0];
    const float* base_res = (const float*)d_in[1];
    const float* lora     = (const float*)d_in[2];
    const float* gate_W   = (const float*)d_in[3];
    const float* gate_b   = (const float*)d_in[4];
    const int*   top_k    = (const int*)d_in[5];
    float* out  = (float*)d_out;
    float* g_ws = (float*)d_ws;  // B*N raw gate logits, fully rewritten per call

    moe_gate_dot<<<dim3(N_ADP, B_SZ), dim3(256), 0, stream>>>(
        (const float4*)x, (const float4*)gate_W, g_ws);

    moe_aggregate<<<dim3(2048, B_SZ), dim3(256), 0, stream>>>(
        (const float4*)base_res, (const float4*)lora, g_ws, gate_b, top_k,
        (float4*)out);
}